// Round 5
// baseline (491.627 us; speedup 1.0000x reference)
//
#include <hip/hip_runtime.h>
#include <hip/hip_fp16.h>

// ---------------------------------------------------------------------------
// CrowdGNN: 2-layer GCN, N=500k nodes, E=8M edges (+ implicit self loops).
// Round-5 (= round-4 with compile fix): layer1 was random-gather bound
// (y = 8MB fp32 > 4MB per-XCD L2).
//  - y stored as fp16x4 (4MB -> L2-resident), z stays fp32 (2MB).
//  - non-temporal loads for the read-once 64MB slot stream (keeps y cached).
//    NOTE: __builtin_nontemporal_load needs a NATIVE vector type, not HIP's
//    longlong2 class -> use ext_vector_type(2) long long.
//  - 512-thread agg blocks, 4-wide unrolled slot loop (16B nt loads,
//    4 concurrent gathers/thread, sentinel-0 instead of tail branches).
// Pipeline: partition (LDS-ranked binning, ~0.5M global atomics total)
//   -> per-bin deg/dinv/y -> per-bin layer1+MLP -> per-bin layer2.
// ---------------------------------------------------------------------------

typedef unsigned long long u64;
typedef long long ll2 __attribute__((ext_vector_type(2)));

#define NPB_SHIFT 9
#define NPB 512
#define MAX_BINS 2048
#define PART_THREADS 1024
#define PART_EPT 16
#define AGG_THREADS 512

struct h4 { __half2 a, b; };

__device__ __forceinline__ float4 h4_to_f4(h4 v) {
    float2 lo = __half22float2(v.a);
    float2 hi = __half22float2(v.b);
    return make_float4(lo.x, lo.y, hi.x, hi.y);
}

// Detect int64 vs int32 edge_index: int64 values < 2^31 => odd words all zero.
__global__ __launch_bounds__(1024)
void k_detect(const unsigned int* __restrict__ idx_words, int nCheck, int* flag) {
    __shared__ int cnt;
    if (threadIdx.x == 0) cnt = 0;
    __syncthreads();
    int local = 0;
    for (int i = threadIdx.x; i < nCheck; i += blockDim.x)
        local += (idx_words[2 * i + 1] != 0u) ? 1 : 0;
    if (local) atomicAdd(&cnt, local);
    __syncthreads();
    if (threadIdx.x == 0) *flag = (cnt < 8) ? 1 : 0;
}

__global__ __launch_bounds__(256)
void k_zero(int* __restrict__ p, int n) {
    int i = blockIdx.x * blockDim.x + threadIdx.x;
    if (i < n) p[i] = 0;
}

// Two-phase binning partition. Block = 1024 thr x 16 edges.
__global__ __launch_bounds__(PART_THREADS)
void k_partition(const void* __restrict__ idx, const float* __restrict__ ew,
                 int* __restrict__ gCnt, u64* __restrict__ slots,
                 int E, int B, int cap, const int* __restrict__ flag) {
    __shared__ int lcnt[MAX_BINS];
    __shared__ int lbase[MAX_BINS];
    const bool is64 = (*flag != 0);
    for (int i = threadIdx.x; i < B; i += PART_THREADS) lcnt[i] = 0;
    __syncthreads();

    const int base_e = blockIdx.x * (PART_EPT * PART_THREADS);
    u64 pay[PART_EPT];
    int binrank[PART_EPT];

#pragma unroll
    for (int i = 0; i < PART_EPT; ++i) {
        int e = base_e + i * PART_THREADS + threadIdx.x;
        binrank[i] = -1;
        if (e < E) {
            int s, d;
            if (is64) {
                const long long* p = (const long long*)idx;
                s = (int)__builtin_nontemporal_load(p + e);
                d = (int)__builtin_nontemporal_load(p + (long long)E + e);
            } else {
                const int* p = (const int*)idx;
                s = __builtin_nontemporal_load(p + e);
                d = __builtin_nontemporal_load(p + E + e);
            }
            float w = __builtin_nontemporal_load(ew + e);
            int bin = d >> NPB_SHIFT;
            unsigned int pk = ((unsigned)(d & (NPB - 1)) << 23) | (unsigned)s;
            pay[i] = ((u64)__float_as_uint(w) << 32) | pk;
            int r = atomicAdd(&lcnt[bin], 1);          // LDS atomic (fast)
            binrank[i] = (bin << 16) | r;              // r < 16384 fits 16b
        }
    }
    __syncthreads();
    for (int b = threadIdx.x; b < B; b += PART_THREADS) {
        int c = lcnt[b];
        lbase[b] = (c > 0) ? atomicAdd(&gCnt[b], c) : 0;  // 1 global atomic/(block,bin)
    }
    __syncthreads();
#pragma unroll
    for (int i = 0; i < PART_EPT; ++i) {
        if (binrank[i] >= 0) {
            int bin = binrank[i] >> 16;
            int r = binrank[i] & 0xFFFF;
            long long pos = (long long)lbase[bin] + r;
            if (pos < cap)
                slots[(size_t)bin * cap + pos] = pay[i];
        }
    }
}

// 4-wide slot fetch with sentinel-0 fill (w=0 -> no-op adds).
__device__ __forceinline__ void load4(const u64* __restrict__ sp, int j, int c,
                                      u64& v0, u64& v1, u64& v2, u64& v3) {
    v0 = v1 = v2 = v3 = 0;
    if (j + 3 < c) {
        ll2 q0 = __builtin_nontemporal_load((const ll2*)(sp + j));
        ll2 q1 = __builtin_nontemporal_load((const ll2*)(sp + j) + 1);
        v0 = (u64)q0.x; v1 = (u64)q0.y; v2 = (u64)q1.x; v3 = (u64)q1.y;
    } else if (j < c) {
        v0 = sp[j];
        if (j + 1 < c) v1 = sp[j + 1];
        if (j + 2 < c) v2 = sp[j + 2];
    }
}

// Per-bin: deg[n] = 1 + sum w; dinv = rsqrt(deg); y[n] = fp16(x[n]*dinv).
__global__ __launch_bounds__(AGG_THREADS, 4)
void k_deg_dinv(const u64* __restrict__ slots, const int* __restrict__ gCnt,
                const float4* __restrict__ x, float* __restrict__ dinv,
                h4* __restrict__ y, int N, int cap) {
    __shared__ float degLds[NPB];
    const int b = blockIdx.x;
    for (int t = threadIdx.x; t < NPB; t += AGG_THREADS) degLds[t] = 0.0f;
    __syncthreads();
    const int c = min(gCnt[b], cap);
    const u64* sp = slots + (size_t)b * cap;
    const int CH = AGG_THREADS * 4;
    for (int base = 0; base < c; base += CH) {
        int j = base + (threadIdx.x << 2);
        u64 v0, v1, v2, v3;
        load4(sp, j, c, v0, v1, v2, v3);
        atomicAdd(&degLds[((unsigned)v0) >> 23], __uint_as_float((unsigned)(v0 >> 32)));
        atomicAdd(&degLds[((unsigned)v1) >> 23], __uint_as_float((unsigned)(v1 >> 32)));
        atomicAdd(&degLds[((unsigned)v2) >> 23], __uint_as_float((unsigned)(v2 >> 32)));
        atomicAdd(&degLds[((unsigned)v3) >> 23], __uint_as_float((unsigned)(v3 >> 32)));
    }
    __syncthreads();
    for (int t = threadIdx.x; t < NPB; t += AGG_THREADS) {
        int n = (b << NPB_SHIFT) + t;
        if (n < N) {
            float di = rsqrtf(1.0f + degLds[t]);
            dinv[n] = di;
            float4 xv = x[n];
            h4 hv;
            hv.a = __floats2half2_rn(xv.x * di, xv.y * di);
            hv.b = __floats2half2_rn(xv.z * di, xv.w * di);
            y[n] = hv;
        }
    }
}

// Per-bin layer1 aggregation + fused MLP: z[n] = dinv[n]*MLP(di*(y[n]+sum w*y[s]))
__global__ __launch_bounds__(AGG_THREADS, 4)
void k_layer1(const u64* __restrict__ slots, const int* __restrict__ gCnt,
              const float* __restrict__ dinv, const h4* __restrict__ yh,
              const float* __restrict__ W1, const float* __restrict__ b1,
              const float* __restrict__ W2, float* __restrict__ z,
              int N, int cap) {
    __shared__ float acc[NPB][4];
    __shared__ float dLds[NPB];
    __shared__ float sW1[64], sb1[16], sW2[16];
    if (threadIdx.x < 64) sW1[threadIdx.x] = W1[threadIdx.x];
    if (threadIdx.x < 16) {
        sb1[threadIdx.x] = b1[threadIdx.x];
        sW2[threadIdx.x] = W2[threadIdx.x];
    }
    const int b = blockIdx.x;
    for (int t = threadIdx.x; t < NPB; t += AGG_THREADS) {
        acc[t][0] = acc[t][1] = acc[t][2] = acc[t][3] = 0.0f;
        int n = (b << NPB_SHIFT) + t;
        dLds[t] = (n < N) ? dinv[n] : 0.0f;
    }
    __syncthreads();
    const int c = min(gCnt[b], cap);
    const u64* sp = slots + (size_t)b * cap;
    const int CH = AGG_THREADS * 4;
    for (int base = 0; base < c; base += CH) {
        int j = base + (threadIdx.x << 2);
        u64 v0, v1, v2, v3;
        load4(sp, j, c, v0, v1, v2, v3);
        unsigned pk0 = (unsigned)v0, pk1 = (unsigned)v1,
                 pk2 = (unsigned)v2, pk3 = (unsigned)v3;
        float w0 = __uint_as_float((unsigned)(v0 >> 32));
        float w1 = __uint_as_float((unsigned)(v1 >> 32));
        float w2 = __uint_as_float((unsigned)(v2 >> 32));
        float w3 = __uint_as_float((unsigned)(v3 >> 32));
        // 4 independent gathers in flight
        h4 g0 = yh[pk0 & 0x7FFFFF];
        h4 g1 = yh[pk1 & 0x7FFFFF];
        h4 g2 = yh[pk2 & 0x7FFFFF];
        h4 g3 = yh[pk3 & 0x7FFFFF];
        float4 f0 = h4_to_f4(g0), f1 = h4_to_f4(g1),
               f2 = h4_to_f4(g2), f3 = h4_to_f4(g3);
        int d0 = pk0 >> 23, d1 = pk1 >> 23, d2 = pk2 >> 23, d3 = pk3 >> 23;
        atomicAdd(&acc[d0][0], w0 * f0.x); atomicAdd(&acc[d0][1], w0 * f0.y);
        atomicAdd(&acc[d0][2], w0 * f0.z); atomicAdd(&acc[d0][3], w0 * f0.w);
        atomicAdd(&acc[d1][0], w1 * f1.x); atomicAdd(&acc[d1][1], w1 * f1.y);
        atomicAdd(&acc[d1][2], w1 * f1.z); atomicAdd(&acc[d1][3], w1 * f1.w);
        atomicAdd(&acc[d2][0], w2 * f2.x); atomicAdd(&acc[d2][1], w2 * f2.y);
        atomicAdd(&acc[d2][2], w2 * f2.z); atomicAdd(&acc[d2][3], w2 * f2.w);
        atomicAdd(&acc[d3][0], w3 * f3.x); atomicAdd(&acc[d3][1], w3 * f3.y);
        atomicAdd(&acc[d3][2], w3 * f3.z); atomicAdd(&acc[d3][3], w3 * f3.w);
    }
    __syncthreads();
    for (int t = threadIdx.x; t < NPB; t += AGG_THREADS) {
        int n = (b << NPB_SHIFT) + t;
        if (n >= N) continue;
        float di = dLds[t];
        float4 yv = h4_to_f4(yh[n]);
        float ax = di * (yv.x + acc[t][0]);
        float ay = di * (yv.y + acc[t][1]);
        float az = di * (yv.z + acc[t][2]);
        float aw = di * (yv.w + acc[t][3]);
        float sacc = 0.0f;
#pragma unroll
        for (int k = 0; k < 16; ++k) {
            float h = ax * sW1[k] + ay * sW1[16 + k] + az * sW1[32 + k]
                    + aw * sW1[48 + k] + sb1[k];
            sacc += fmaxf(h, 0.0f) * sW2[k];
        }
        z[n] = sacc * di;
    }
}

// Per-bin layer2: out[n] = di*(z[n] + sum w*z[s]) + b2
__global__ __launch_bounds__(AGG_THREADS, 4)
void k_layer2(const u64* __restrict__ slots, const int* __restrict__ gCnt,
              const float* __restrict__ dinv, const float* __restrict__ z,
              const float* __restrict__ b2, float* __restrict__ out,
              int N, int cap) {
    __shared__ float accs[NPB];
    __shared__ float dLds[NPB];
    const int b = blockIdx.x;
    for (int t = threadIdx.x; t < NPB; t += AGG_THREADS) {
        accs[t] = 0.0f;
        int n = (b << NPB_SHIFT) + t;
        dLds[t] = (n < N) ? dinv[n] : 0.0f;
    }
    __syncthreads();
    const int c = min(gCnt[b], cap);
    const u64* sp = slots + (size_t)b * cap;
    const int CH = AGG_THREADS * 4;
    for (int base = 0; base < c; base += CH) {
        int j = base + (threadIdx.x << 2);
        u64 v0, v1, v2, v3;
        load4(sp, j, c, v0, v1, v2, v3);
        unsigned pk0 = (unsigned)v0, pk1 = (unsigned)v1,
                 pk2 = (unsigned)v2, pk3 = (unsigned)v3;
        float z0 = z[pk0 & 0x7FFFFF];
        float z1 = z[pk1 & 0x7FFFFF];
        float z2 = z[pk2 & 0x7FFFFF];
        float z3 = z[pk3 & 0x7FFFFF];
        atomicAdd(&accs[pk0 >> 23], __uint_as_float((unsigned)(v0 >> 32)) * z0);
        atomicAdd(&accs[pk1 >> 23], __uint_as_float((unsigned)(v1 >> 32)) * z1);
        atomicAdd(&accs[pk2 >> 23], __uint_as_float((unsigned)(v2 >> 32)) * z2);
        atomicAdd(&accs[pk3 >> 23], __uint_as_float((unsigned)(v3 >> 32)) * z3);
    }
    __syncthreads();
    const float bb2 = b2[0];
    for (int t = threadIdx.x; t < NPB; t += AGG_THREADS) {
        int n = (b << NPB_SHIFT) + t;
        if (n < N) out[n] = dLds[t] * (z[n] + accs[t]) + bb2;
    }
}

// ------------------------- fallback (round-1) path -------------------------
__global__ __launch_bounds__(256)
void k_init(float* __restrict__ deg, int N) {
    int i = blockIdx.x * blockDim.x + threadIdx.x;
    if (i < N) deg[i] = 1.0f;
}

__global__ __launch_bounds__(256)
void k_deg(const void* __restrict__ idx, const float* __restrict__ ew,
           float* __restrict__ deg, int E, const int* __restrict__ flag) {
    const bool is64 = (*flag != 0);
    const int stride = gridDim.x * blockDim.x;
    for (int e = blockIdx.x * blockDim.x + threadIdx.x; e < E; e += stride) {
        int d = is64 ? (int)((const long long*)idx)[(long long)E + e]
                     : ((const int*)idx)[E + e];
        atomicAdd(deg + d, ew[e]);
    }
}

__global__ __launch_bounds__(256)
void k_dinv_accx(float* __restrict__ deg_dinv, const float4* __restrict__ x,
                 float4* __restrict__ accx, int N) {
    int n = blockIdx.x * blockDim.x + threadIdx.x;
    if (n >= N) return;
    float dg = deg_dinv[n];
    float di = (dg > 0.0f) ? rsqrtf(dg) : 0.0f;
    deg_dinv[n] = di;
    float sn = di * di;
    float4 xv = x[n];
    accx[n] = make_float4(xv.x * sn, xv.y * sn, xv.z * sn, xv.w * sn);
}

__global__ __launch_bounds__(256)
void k_scatter1(const void* __restrict__ idx, const float* __restrict__ ew,
                const float* __restrict__ dinv, const float4* __restrict__ x,
                float* __restrict__ accx, int E, const int* __restrict__ flag) {
    const bool is64 = (*flag != 0);
    const int stride = gridDim.x * blockDim.x;
    for (int e = blockIdx.x * blockDim.x + threadIdx.x; e < E; e += stride) {
        int s, d;
        if (is64) {
            const long long* p = (const long long*)idx;
            s = (int)p[e]; d = (int)p[(long long)E + e];
        } else {
            const int* p = (const int*)idx;
            s = p[e]; d = p[E + e];
        }
        float nm = dinv[s] * ew[e] * dinv[d];
        float4 xv = x[s];
        float* dp = accx + (size_t)d * 4;
        atomicAdd(dp + 0, nm * xv.x);
        atomicAdd(dp + 1, nm * xv.y);
        atomicAdd(dp + 2, nm * xv.z);
        atomicAdd(dp + 3, nm * xv.w);
    }
}

__global__ __launch_bounds__(256)
void k_node2(const float4* __restrict__ accx, const float* __restrict__ dinv,
             const float* __restrict__ W1, const float* __restrict__ b1,
             const float* __restrict__ W2, const float* __restrict__ b2,
             float* __restrict__ s2, float* __restrict__ out, int N) {
    __shared__ float sW1[64], sb1[16], sW2[16];
    if (threadIdx.x < 64) sW1[threadIdx.x] = W1[threadIdx.x];
    if (threadIdx.x < 16) {
        sb1[threadIdx.x] = b1[threadIdx.x];
        sW2[threadIdx.x] = W2[threadIdx.x];
    }
    __syncthreads();
    int n = blockIdx.x * blockDim.x + threadIdx.x;
    if (n >= N) return;
    float bb2 = b2[0];
    float4 a = accx[n];
    float acc = 0.0f;
#pragma unroll
    for (int k = 0; k < 16; ++k) {
        float h = a.x * sW1[k] + a.y * sW1[16 + k] + a.z * sW1[32 + k]
                + a.w * sW1[48 + k] + sb1[k];
        acc += fmaxf(h, 0.0f) * sW2[k];
    }
    s2[n] = acc;
    float di = dinv[n];
    out[n] = acc * di * di + bb2;
}

__global__ __launch_bounds__(256)
void k_scatter2(const void* __restrict__ idx, const float* __restrict__ ew,
                const float* __restrict__ dinv, const float* __restrict__ s2,
                float* __restrict__ out, int E, const int* __restrict__ flag) {
    const bool is64 = (*flag != 0);
    const int stride = gridDim.x * blockDim.x;
    for (int e = blockIdx.x * blockDim.x + threadIdx.x; e < E; e += stride) {
        int s, d;
        if (is64) {
            const long long* p = (const long long*)idx;
            s = (int)p[e]; d = (int)p[(long long)E + e];
        } else {
            const int* p = (const int*)idx;
            s = p[e]; d = p[E + e];
        }
        float nm = dinv[s] * ew[e] * dinv[d];
        atomicAdd(out + d, nm * s2[s]);
    }
}

// ---------------------------------------------------------------------------
extern "C" void kernel_launch(void* const* d_in, const int* in_sizes, int n_in,
                              void* d_out, int out_size, void* d_ws, size_t ws_size,
                              hipStream_t stream) {
    const float* x   = (const float*)d_in[0];
    const void*  eix = d_in[1];
    const float* ew  = (const float*)d_in[2];
    const float* W1  = (const float*)d_in[3];
    const float* b1  = (const float*)d_in[4];
    const float* W2  = (const float*)d_in[5];
    const float* b2  = (const float*)d_in[6];
    float* out = (float*)d_out;

    const int N = in_sizes[0] / 4;   // x is [N,4]
    const int E = in_sizes[2];       // edge_weight is [E]

    const int B = (N + NPB - 1) >> NPB_SHIFT;
    int cap = (E / B + 2048 + 3) & ~3;   // mean + ~23 sigma, multiple of 4
    const int nCheck = (E < 65536) ? E : 65536;

    // ws: y [N h4=8B] | slots [B*cap u64] | gCnt [B] | dinv [N] | z [N] | flag
    size_t need = (size_t)N * 8 + (size_t)B * cap * 8
                + (size_t)B * 4 + (size_t)N * 8 + 256;

    if (B <= MAX_BINS && N < (1 << 23) && ws_size >= need) {
        h4* y = (h4*)d_ws;
        u64* slots = (u64*)(y + N);
        int*   gCnt = (int*)(slots + (size_t)B * cap);
        float* dinv = (float*)(gCnt + B);
        float* z    = dinv + N;
        int*   flag = (int*)(z + N);

        const int part_blocks = (E + PART_EPT * PART_THREADS - 1) / (PART_EPT * PART_THREADS);

        k_zero<<<(B + 255) / 256, 256, 0, stream>>>(gCnt, B);
        k_detect<<<1, 1024, 0, stream>>>((const unsigned int*)eix, nCheck, flag);
        k_partition<<<part_blocks, PART_THREADS, 0, stream>>>(eix, ew, gCnt, slots,
                                                              E, B, cap, flag);
        k_deg_dinv<<<B, AGG_THREADS, 0, stream>>>(slots, gCnt, (const float4*)x,
                                                  dinv, y, N, cap);
        k_layer1<<<B, AGG_THREADS, 0, stream>>>(slots, gCnt, dinv, y, W1, b1, W2,
                                                z, N, cap);
        k_layer2<<<B, AGG_THREADS, 0, stream>>>(slots, gCnt, dinv, z, b2, out, N, cap);
    } else {
        // fallback: direct atomic scatter (round-1)
        const int nb_n = (N + 255) / 256;
        const int nb_e = min((E + 255) / 256, 16384);
        float* deg  = (float*)d_ws;
        float* accx = deg + N;
        float* s2   = accx + (size_t)4 * N;
        int*   flag = (int*)(s2 + N);

        k_init<<<nb_n, 256, 0, stream>>>(deg, N);
        k_detect<<<1, 1024, 0, stream>>>((const unsigned int*)eix, nCheck, flag);
        k_deg<<<nb_e, 256, 0, stream>>>(eix, ew, deg, E, flag);
        k_dinv_accx<<<nb_n, 256, 0, stream>>>(deg, (const float4*)x, (float4*)accx, N);
        k_scatter1<<<nb_e, 256, 0, stream>>>(eix, ew, deg, (const float4*)x, accx, E, flag);
        k_node2<<<nb_n, 256, 0, stream>>>((const float4*)accx, deg, W1, b1, W2, b2, s2, out, N);
        k_scatter2<<<nb_e, 256, 0, stream>>>(eix, ew, deg, s2, out, E, flag);
    }
}

// Round 6
// 484.567 us; speedup vs baseline: 1.0146x; 1.0146x over previous
//
#include <hip/hip_runtime.h>
#include <hip/hip_fp16.h>

// ---------------------------------------------------------------------------
// CrowdGNN: 2-layer GCN, N=500k nodes, E=8M edges (+ implicit self loops).
// Round-6: round-5 post-mortem showed nontemporal slot loads caused the
// regression (56MB at 240GB/s effective = uncached low-concurrency reads).
//  - slots read with NORMAL cached loads (L3-resident, written by partition);
//    nt kept ONLY for the read-once 160MB edge arrays in k_partition.
//  - acc LDS array padded [512][5]: acc[dl][ch] at stride 4 hit only 8 banks
//    for a fixed channel (addr=(dl*4+ch)*4, dl*4%32 has 8 values) -> 8-way
//    atomic serialization; stride 5 (gcd(5,32)=1) spreads all 32 banks.
//  - keep: fp16 y (4MB, L2-resident), 4-wide unrolled slot loop, 512-thr
//    agg blocks, LDS-ranked binning partition (~0.5M global atomics).
// ---------------------------------------------------------------------------

typedef unsigned long long u64;
typedef long long ll2 __attribute__((ext_vector_type(2)));

#define NPB_SHIFT 9
#define NPB 512
#define MAX_BINS 2048
#define PART_THREADS 1024
#define PART_EPT 16
#define AGG_THREADS 512

struct h4 { __half2 a, b; };

__device__ __forceinline__ float4 h4_to_f4(h4 v) {
    float2 lo = __half22float2(v.a);
    float2 hi = __half22float2(v.b);
    return make_float4(lo.x, lo.y, hi.x, hi.y);
}

// Detect int64 vs int32 edge_index: int64 values < 2^31 => odd words all zero.
__global__ __launch_bounds__(1024)
void k_detect(const unsigned int* __restrict__ idx_words, int nCheck, int* flag) {
    __shared__ int cnt;
    if (threadIdx.x == 0) cnt = 0;
    __syncthreads();
    int local = 0;
    for (int i = threadIdx.x; i < nCheck; i += blockDim.x)
        local += (idx_words[2 * i + 1] != 0u) ? 1 : 0;
    if (local) atomicAdd(&cnt, local);
    __syncthreads();
    if (threadIdx.x == 0) *flag = (cnt < 8) ? 1 : 0;
}

__global__ __launch_bounds__(256)
void k_zero(int* __restrict__ p, int n) {
    int i = blockIdx.x * blockDim.x + threadIdx.x;
    if (i < n) p[i] = 0;
}

// Two-phase binning partition. Block = 1024 thr x 16 edges.
__global__ __launch_bounds__(PART_THREADS)
void k_partition(const void* __restrict__ idx, const float* __restrict__ ew,
                 int* __restrict__ gCnt, u64* __restrict__ slots,
                 int E, int B, int cap, const int* __restrict__ flag) {
    __shared__ int lcnt[MAX_BINS];
    __shared__ int lbase[MAX_BINS];
    const bool is64 = (*flag != 0);
    for (int i = threadIdx.x; i < B; i += PART_THREADS) lcnt[i] = 0;
    __syncthreads();

    const int base_e = blockIdx.x * (PART_EPT * PART_THREADS);
    u64 pay[PART_EPT];
    int binrank[PART_EPT];

#pragma unroll
    for (int i = 0; i < PART_EPT; ++i) {
        int e = base_e + i * PART_THREADS + threadIdx.x;
        binrank[i] = -1;
        if (e < E) {
            int s, d;
            if (is64) {
                const long long* p = (const long long*)idx;
                s = (int)__builtin_nontemporal_load(p + e);
                d = (int)__builtin_nontemporal_load(p + (long long)E + e);
            } else {
                const int* p = (const int*)idx;
                s = __builtin_nontemporal_load(p + e);
                d = __builtin_nontemporal_load(p + E + e);
            }
            float w = __builtin_nontemporal_load(ew + e);
            int bin = d >> NPB_SHIFT;
            unsigned int pk = ((unsigned)(d & (NPB - 1)) << 23) | (unsigned)s;
            pay[i] = ((u64)__float_as_uint(w) << 32) | pk;
            int r = atomicAdd(&lcnt[bin], 1);          // LDS atomic (fast)
            binrank[i] = (bin << 16) | r;              // r < 16384 fits 16b
        }
    }
    __syncthreads();
    for (int b = threadIdx.x; b < B; b += PART_THREADS) {
        int c = lcnt[b];
        lbase[b] = (c > 0) ? atomicAdd(&gCnt[b], c) : 0;  // 1 global atomic/(block,bin)
    }
    __syncthreads();
#pragma unroll
    for (int i = 0; i < PART_EPT; ++i) {
        if (binrank[i] >= 0) {
            int bin = binrank[i] >> 16;
            int r = binrank[i] & 0xFFFF;
            long long pos = (long long)lbase[bin] + r;
            if (pos < cap)
                slots[(size_t)bin * cap + pos] = pay[i];
        }
    }
}

// 4-wide slot fetch with sentinel-0 fill (w=0 -> no-op adds). CACHED loads.
__device__ __forceinline__ void load4(const u64* __restrict__ sp, int j, int c,
                                      u64& v0, u64& v1, u64& v2, u64& v3) {
    v0 = v1 = v2 = v3 = 0;
    if (j + 3 < c) {
        ll2 q0 = *((const ll2*)(sp + j));
        ll2 q1 = *((const ll2*)(sp + j) + 1);
        v0 = (u64)q0.x; v1 = (u64)q0.y; v2 = (u64)q1.x; v3 = (u64)q1.y;
    } else if (j < c) {
        v0 = sp[j];
        if (j + 1 < c) v1 = sp[j + 1];
        if (j + 2 < c) v2 = sp[j + 2];
    }
}

// Per-bin: deg[n] = 1 + sum w; dinv = rsqrt(deg); y[n] = fp16(x[n]*dinv).
__global__ __launch_bounds__(AGG_THREADS, 4)
void k_deg_dinv(const u64* __restrict__ slots, const int* __restrict__ gCnt,
                const float4* __restrict__ x, float* __restrict__ dinv,
                h4* __restrict__ y, int N, int cap) {
    __shared__ float degLds[NPB];
    const int b = blockIdx.x;
    for (int t = threadIdx.x; t < NPB; t += AGG_THREADS) degLds[t] = 0.0f;
    __syncthreads();
    const int c = min(gCnt[b], cap);
    const u64* sp = slots + (size_t)b * cap;
    const int CH = AGG_THREADS * 4;
    for (int base = 0; base < c; base += CH) {
        int j = base + (threadIdx.x << 2);
        u64 v0, v1, v2, v3;
        load4(sp, j, c, v0, v1, v2, v3);
        atomicAdd(&degLds[((unsigned)v0) >> 23], __uint_as_float((unsigned)(v0 >> 32)));
        atomicAdd(&degLds[((unsigned)v1) >> 23], __uint_as_float((unsigned)(v1 >> 32)));
        atomicAdd(&degLds[((unsigned)v2) >> 23], __uint_as_float((unsigned)(v2 >> 32)));
        atomicAdd(&degLds[((unsigned)v3) >> 23], __uint_as_float((unsigned)(v3 >> 32)));
    }
    __syncthreads();
    for (int t = threadIdx.x; t < NPB; t += AGG_THREADS) {
        int n = (b << NPB_SHIFT) + t;
        if (n < N) {
            float di = rsqrtf(1.0f + degLds[t]);
            dinv[n] = di;
            float4 xv = x[n];
            h4 hv;
            hv.a = __floats2half2_rn(xv.x * di, xv.y * di);
            hv.b = __floats2half2_rn(xv.z * di, xv.w * di);
            y[n] = hv;
        }
    }
}

// Per-bin layer1 aggregation + fused MLP: z[n] = dinv[n]*MLP(di*(y[n]+sum w*y[s]))
__global__ __launch_bounds__(AGG_THREADS, 4)
void k_layer1(const u64* __restrict__ slots, const int* __restrict__ gCnt,
              const float* __restrict__ dinv, const h4* __restrict__ yh,
              const float* __restrict__ W1, const float* __restrict__ b1,
              const float* __restrict__ W2, float* __restrict__ z,
              int N, int cap) {
    __shared__ float acc[NPB][5];   // stride 5: gcd(5,32)=1 -> 32-bank spread
    __shared__ float dLds[NPB];
    __shared__ float sW1[64], sb1[16], sW2[16];
    if (threadIdx.x < 64) sW1[threadIdx.x] = W1[threadIdx.x];
    if (threadIdx.x < 16) {
        sb1[threadIdx.x] = b1[threadIdx.x];
        sW2[threadIdx.x] = W2[threadIdx.x];
    }
    const int b = blockIdx.x;
    for (int t = threadIdx.x; t < NPB; t += AGG_THREADS) {
        acc[t][0] = acc[t][1] = acc[t][2] = acc[t][3] = 0.0f;
        int n = (b << NPB_SHIFT) + t;
        dLds[t] = (n < N) ? dinv[n] : 0.0f;
    }
    __syncthreads();
    const int c = min(gCnt[b], cap);
    const u64* sp = slots + (size_t)b * cap;
    const int CH = AGG_THREADS * 4;
    for (int base = 0; base < c; base += CH) {
        int j = base + (threadIdx.x << 2);
        u64 v0, v1, v2, v3;
        load4(sp, j, c, v0, v1, v2, v3);
        unsigned pk0 = (unsigned)v0, pk1 = (unsigned)v1,
                 pk2 = (unsigned)v2, pk3 = (unsigned)v3;
        float w0 = __uint_as_float((unsigned)(v0 >> 32));
        float w1 = __uint_as_float((unsigned)(v1 >> 32));
        float w2 = __uint_as_float((unsigned)(v2 >> 32));
        float w3 = __uint_as_float((unsigned)(v3 >> 32));
        // 4 independent gathers in flight
        h4 g0 = yh[pk0 & 0x7FFFFF];
        h4 g1 = yh[pk1 & 0x7FFFFF];
        h4 g2 = yh[pk2 & 0x7FFFFF];
        h4 g3 = yh[pk3 & 0x7FFFFF];
        float4 f0 = h4_to_f4(g0), f1 = h4_to_f4(g1),
               f2 = h4_to_f4(g2), f3 = h4_to_f4(g3);
        int d0 = pk0 >> 23, d1 = pk1 >> 23, d2 = pk2 >> 23, d3 = pk3 >> 23;
        atomicAdd(&acc[d0][0], w0 * f0.x); atomicAdd(&acc[d0][1], w0 * f0.y);
        atomicAdd(&acc[d0][2], w0 * f0.z); atomicAdd(&acc[d0][3], w0 * f0.w);
        atomicAdd(&acc[d1][0], w1 * f1.x); atomicAdd(&acc[d1][1], w1 * f1.y);
        atomicAdd(&acc[d1][2], w1 * f1.z); atomicAdd(&acc[d1][3], w1 * f1.w);
        atomicAdd(&acc[d2][0], w2 * f2.x); atomicAdd(&acc[d2][1], w2 * f2.y);
        atomicAdd(&acc[d2][2], w2 * f2.z); atomicAdd(&acc[d2][3], w2 * f2.w);
        atomicAdd(&acc[d3][0], w3 * f3.x); atomicAdd(&acc[d3][1], w3 * f3.y);
        atomicAdd(&acc[d3][2], w3 * f3.z); atomicAdd(&acc[d3][3], w3 * f3.w);
    }
    __syncthreads();
    for (int t = threadIdx.x; t < NPB; t += AGG_THREADS) {
        int n = (b << NPB_SHIFT) + t;
        if (n >= N) continue;
        float di = dLds[t];
        float4 yv = h4_to_f4(yh[n]);
        float ax = di * (yv.x + acc[t][0]);
        float ay = di * (yv.y + acc[t][1]);
        float az = di * (yv.z + acc[t][2]);
        float aw = di * (yv.w + acc[t][3]);
        float sacc = 0.0f;
#pragma unroll
        for (int k = 0; k < 16; ++k) {
            float h = ax * sW1[k] + ay * sW1[16 + k] + az * sW1[32 + k]
                    + aw * sW1[48 + k] + sb1[k];
            sacc += fmaxf(h, 0.0f) * sW2[k];
        }
        z[n] = sacc * di;
    }
}

// Per-bin layer2: out[n] = di*(z[n] + sum w*z[s]) + b2
__global__ __launch_bounds__(AGG_THREADS, 4)
void k_layer2(const u64* __restrict__ slots, const int* __restrict__ gCnt,
              const float* __restrict__ dinv, const float* __restrict__ z,
              const float* __restrict__ b2, float* __restrict__ out,
              int N, int cap) {
    __shared__ float accs[NPB];
    __shared__ float dLds[NPB];
    const int b = blockIdx.x;
    for (int t = threadIdx.x; t < NPB; t += AGG_THREADS) {
        accs[t] = 0.0f;
        int n = (b << NPB_SHIFT) + t;
        dLds[t] = (n < N) ? dinv[n] : 0.0f;
    }
    __syncthreads();
    const int c = min(gCnt[b], cap);
    const u64* sp = slots + (size_t)b * cap;
    const int CH = AGG_THREADS * 4;
    for (int base = 0; base < c; base += CH) {
        int j = base + (threadIdx.x << 2);
        u64 v0, v1, v2, v3;
        load4(sp, j, c, v0, v1, v2, v3);
        unsigned pk0 = (unsigned)v0, pk1 = (unsigned)v1,
                 pk2 = (unsigned)v2, pk3 = (unsigned)v3;
        float z0 = z[pk0 & 0x7FFFFF];
        float z1 = z[pk1 & 0x7FFFFF];
        float z2 = z[pk2 & 0x7FFFFF];
        float z3 = z[pk3 & 0x7FFFFF];
        atomicAdd(&accs[pk0 >> 23], __uint_as_float((unsigned)(v0 >> 32)) * z0);
        atomicAdd(&accs[pk1 >> 23], __uint_as_float((unsigned)(v1 >> 32)) * z1);
        atomicAdd(&accs[pk2 >> 23], __uint_as_float((unsigned)(v2 >> 32)) * z2);
        atomicAdd(&accs[pk3 >> 23], __uint_as_float((unsigned)(v3 >> 32)) * z3);
    }
    __syncthreads();
    const float bb2 = b2[0];
    for (int t = threadIdx.x; t < NPB; t += AGG_THREADS) {
        int n = (b << NPB_SHIFT) + t;
        if (n < N) out[n] = dLds[t] * (z[n] + accs[t]) + bb2;
    }
}

// ------------------------- fallback (round-1) path -------------------------
__global__ __launch_bounds__(256)
void k_init(float* __restrict__ deg, int N) {
    int i = blockIdx.x * blockDim.x + threadIdx.x;
    if (i < N) deg[i] = 1.0f;
}

__global__ __launch_bounds__(256)
void k_deg(const void* __restrict__ idx, const float* __restrict__ ew,
           float* __restrict__ deg, int E, const int* __restrict__ flag) {
    const bool is64 = (*flag != 0);
    const int stride = gridDim.x * blockDim.x;
    for (int e = blockIdx.x * blockDim.x + threadIdx.x; e < E; e += stride) {
        int d = is64 ? (int)((const long long*)idx)[(long long)E + e]
                     : ((const int*)idx)[E + e];
        atomicAdd(deg + d, ew[e]);
    }
}

__global__ __launch_bounds__(256)
void k_dinv_accx(float* __restrict__ deg_dinv, const float4* __restrict__ x,
                 float4* __restrict__ accx, int N) {
    int n = blockIdx.x * blockDim.x + threadIdx.x;
    if (n >= N) return;
    float dg = deg_dinv[n];
    float di = (dg > 0.0f) ? rsqrtf(dg) : 0.0f;
    deg_dinv[n] = di;
    float sn = di * di;
    float4 xv = x[n];
    accx[n] = make_float4(xv.x * sn, xv.y * sn, xv.z * sn, xv.w * sn);
}

__global__ __launch_bounds__(256)
void k_scatter1(const void* __restrict__ idx, const float* __restrict__ ew,
                const float* __restrict__ dinv, const float4* __restrict__ x,
                float* __restrict__ accx, int E, const int* __restrict__ flag) {
    const bool is64 = (*flag != 0);
    const int stride = gridDim.x * blockDim.x;
    for (int e = blockIdx.x * blockDim.x + threadIdx.x; e < E; e += stride) {
        int s, d;
        if (is64) {
            const long long* p = (const long long*)idx;
            s = (int)p[e]; d = (int)p[(long long)E + e];
        } else {
            const int* p = (const int*)idx;
            s = p[e]; d = p[E + e];
        }
        float nm = dinv[s] * ew[e] * dinv[d];
        float4 xv = x[s];
        float* dp = accx + (size_t)d * 4;
        atomicAdd(dp + 0, nm * xv.x);
        atomicAdd(dp + 1, nm * xv.y);
        atomicAdd(dp + 2, nm * xv.z);
        atomicAdd(dp + 3, nm * xv.w);
    }
}

__global__ __launch_bounds__(256)
void k_node2(const float4* __restrict__ accx, const float* __restrict__ dinv,
             const float* __restrict__ W1, const float* __restrict__ b1,
             const float* __restrict__ W2, const float* __restrict__ b2,
             float* __restrict__ s2, float* __restrict__ out, int N) {
    __shared__ float sW1[64], sb1[16], sW2[16];
    if (threadIdx.x < 64) sW1[threadIdx.x] = W1[threadIdx.x];
    if (threadIdx.x < 16) {
        sb1[threadIdx.x] = b1[threadIdx.x];
        sW2[threadIdx.x] = W2[threadIdx.x];
    }
    __syncthreads();
    int n = blockIdx.x * blockDim.x + threadIdx.x;
    if (n >= N) return;
    float bb2 = b2[0];
    float4 a = accx[n];
    float acc = 0.0f;
#pragma unroll
    for (int k = 0; k < 16; ++k) {
        float h = a.x * sW1[k] + a.y * sW1[16 + k] + a.z * sW1[32 + k]
                + a.w * sW1[48 + k] + sb1[k];
        acc += fmaxf(h, 0.0f) * sW2[k];
    }
    s2[n] = acc;
    float di = dinv[n];
    out[n] = acc * di * di + bb2;
}

__global__ __launch_bounds__(256)
void k_scatter2(const void* __restrict__ idx, const float* __restrict__ ew,
                const float* __restrict__ dinv, const float* __restrict__ s2,
                float* __restrict__ out, int E, const int* __restrict__ flag) {
    const bool is64 = (*flag != 0);
    const int stride = gridDim.x * blockDim.x;
    for (int e = blockIdx.x * blockDim.x + threadIdx.x; e < E; e += stride) {
        int s, d;
        if (is64) {
            const long long* p = (const long long*)idx;
            s = (int)p[e]; d = (int)p[(long long)E + e];
        } else {
            const int* p = (const int*)idx;
            s = p[e]; d = p[E + e];
        }
        float nm = dinv[s] * ew[e] * dinv[d];
        atomicAdd(out + d, nm * s2[s]);
    }
}

// ---------------------------------------------------------------------------
extern "C" void kernel_launch(void* const* d_in, const int* in_sizes, int n_in,
                              void* d_out, int out_size, void* d_ws, size_t ws_size,
                              hipStream_t stream) {
    const float* x   = (const float*)d_in[0];
    const void*  eix = d_in[1];
    const float* ew  = (const float*)d_in[2];
    const float* W1  = (const float*)d_in[3];
    const float* b1  = (const float*)d_in[4];
    const float* W2  = (const float*)d_in[5];
    const float* b2  = (const float*)d_in[6];
    float* out = (float*)d_out;

    const int N = in_sizes[0] / 4;   // x is [N,4]
    const int E = in_sizes[2];       // edge_weight is [E]

    const int B = (N + NPB - 1) >> NPB_SHIFT;
    int cap = (E / B + 2048 + 3) & ~3;   // mean + ~23 sigma, multiple of 4
    const int nCheck = (E < 65536) ? E : 65536;

    // ws: y [N h4=8B] | slots [B*cap u64] | gCnt [B] | dinv [N] | z [N] | flag
    size_t need = (size_t)N * 8 + (size_t)B * cap * 8
                + (size_t)B * 4 + (size_t)N * 8 + 256;

    if (B <= MAX_BINS && N < (1 << 23) && ws_size >= need) {
        h4* y = (h4*)d_ws;
        u64* slots = (u64*)(y + N);
        int*   gCnt = (int*)(slots + (size_t)B * cap);
        float* dinv = (float*)(gCnt + B);
        float* z    = dinv + N;
        int*   flag = (int*)(z + N);

        const int part_blocks = (E + PART_EPT * PART_THREADS - 1) / (PART_EPT * PART_THREADS);

        k_zero<<<(B + 255) / 256, 256, 0, stream>>>(gCnt, B);
        k_detect<<<1, 1024, 0, stream>>>((const unsigned int*)eix, nCheck, flag);
        k_partition<<<part_blocks, PART_THREADS, 0, stream>>>(eix, ew, gCnt, slots,
                                                              E, B, cap, flag);
        k_deg_dinv<<<B, AGG_THREADS, 0, stream>>>(slots, gCnt, (const float4*)x,
                                                  dinv, y, N, cap);
        k_layer1<<<B, AGG_THREADS, 0, stream>>>(slots, gCnt, dinv, y, W1, b1, W2,
                                                z, N, cap);
        k_layer2<<<B, AGG_THREADS, 0, stream>>>(slots, gCnt, dinv, z, b2, out, N, cap);
    } else {
        // fallback: direct atomic scatter (round-1)
        const int nb_n = (N + 255) / 256;
        const int nb_e = min((E + 255) / 256, 16384);
        float* deg  = (float*)d_ws;
        float* accx = deg + N;
        float* s2   = accx + (size_t)4 * N;
        int*   flag = (int*)(s2 + N);

        k_init<<<nb_n, 256, 0, stream>>>(deg, N);
        k_detect<<<1, 1024, 0, stream>>>((const unsigned int*)eix, nCheck, flag);
        k_deg<<<nb_e, 256, 0, stream>>>(eix, ew, deg, E, flag);
        k_dinv_accx<<<nb_n, 256, 0, stream>>>(deg, (const float4*)x, (float4*)accx, N);
        k_scatter1<<<nb_e, 256, 0, stream>>>(eix, ew, deg, (const float4*)x, accx, E, flag);
        k_node2<<<nb_n, 256, 0, stream>>>((const float4*)accx, deg, W1, b1, W2, b2, s2, out, N);
        k_scatter2<<<nb_e, 256, 0, stream>>>(eix, ew, deg, s2, out, E, flag);
    }
}

// Round 7
// 256.354 us; speedup vs baseline: 1.9178x; 1.8902x over previous
//
#include <hip/hip_runtime.h>
#include <hip/hip_fp16.h>

// ---------------------------------------------------------------------------
// CrowdGNN: 2-layer GCN, N=500k nodes, E=8M edges (+ implicit self loops).
// Round-7: the ~233us layer1 invariant was fp32 LDS atomicAdd compiled as a
// CAS retry loop (no -munsafe-fp-atomics in harness compile line -> no native
// ds_add_f32). Replace ALL hot-loop fp32 LDS atomics with FIXED-POINT INT
// atomics (ds_add_u32 is native, flag-free):
//   deg:    scale 2^24 (|deg| < 128)
//   layer1: scale 2^22 (|acc| < 512;  |w*y| <= ~5.3, deg <= ~50)
//   layer2: scale 2^20 (|acc| < 2048)
// Rounding err ~1e-6 << fp16-y quantization (2e-3) << threshold (2e-2).
// Keep: binned slot build (int atomics, already native), fp16 y table (4MB,
// L2-resident), 4-wide unrolled slot loop, nt loads only in partition.
// ---------------------------------------------------------------------------

typedef unsigned long long u64;
typedef long long ll2 __attribute__((ext_vector_type(2)));

#define NPB_SHIFT 9
#define NPB 512
#define MAX_BINS 2048
#define PART_THREADS 1024
#define PART_EPT 16
#define AGG_THREADS 512

#define DEG_SCALE  16777216.0f   // 2^24
#define DEG_INV    (1.0f / 16777216.0f)
#define A1_SCALE   4194304.0f    // 2^22
#define A1_INV     (1.0f / 4194304.0f)
#define A2_SCALE   1048576.0f    // 2^20
#define A2_INV     (1.0f / 1048576.0f)

struct h4 { __half2 a, b; };

__device__ __forceinline__ float4 h4_to_f4(h4 v) {
    float2 lo = __half22float2(v.a);
    float2 hi = __half22float2(v.b);
    return make_float4(lo.x, lo.y, hi.x, hi.y);
}

// Detect int64 vs int32 edge_index: int64 values < 2^31 => odd words all zero.
__global__ __launch_bounds__(1024)
void k_detect(const unsigned int* __restrict__ idx_words, int nCheck, int* flag) {
    __shared__ int cnt;
    if (threadIdx.x == 0) cnt = 0;
    __syncthreads();
    int local = 0;
    for (int i = threadIdx.x; i < nCheck; i += blockDim.x)
        local += (idx_words[2 * i + 1] != 0u) ? 1 : 0;
    if (local) atomicAdd(&cnt, local);
    __syncthreads();
    if (threadIdx.x == 0) *flag = (cnt < 8) ? 1 : 0;
}

__global__ __launch_bounds__(256)
void k_zero(int* __restrict__ p, int n) {
    int i = blockIdx.x * blockDim.x + threadIdx.x;
    if (i < n) p[i] = 0;
}

// Two-phase binning partition. Block = 1024 thr x 16 edges.
__global__ __launch_bounds__(PART_THREADS)
void k_partition(const void* __restrict__ idx, const float* __restrict__ ew,
                 int* __restrict__ gCnt, u64* __restrict__ slots,
                 int E, int B, int cap, const int* __restrict__ flag) {
    __shared__ int lcnt[MAX_BINS];
    __shared__ int lbase[MAX_BINS];
    const bool is64 = (*flag != 0);
    for (int i = threadIdx.x; i < B; i += PART_THREADS) lcnt[i] = 0;
    __syncthreads();

    const int base_e = blockIdx.x * (PART_EPT * PART_THREADS);
    u64 pay[PART_EPT];
    int binrank[PART_EPT];

#pragma unroll
    for (int i = 0; i < PART_EPT; ++i) {
        int e = base_e + i * PART_THREADS + threadIdx.x;
        binrank[i] = -1;
        if (e < E) {
            int s, d;
            if (is64) {
                const long long* p = (const long long*)idx;
                s = (int)__builtin_nontemporal_load(p + e);
                d = (int)__builtin_nontemporal_load(p + (long long)E + e);
            } else {
                const int* p = (const int*)idx;
                s = __builtin_nontemporal_load(p + e);
                d = __builtin_nontemporal_load(p + E + e);
            }
            float w = __builtin_nontemporal_load(ew + e);
            int bin = d >> NPB_SHIFT;
            unsigned int pk = ((unsigned)(d & (NPB - 1)) << 23) | (unsigned)s;
            pay[i] = ((u64)__float_as_uint(w) << 32) | pk;
            int r = atomicAdd(&lcnt[bin], 1);          // native ds_add_u32
            binrank[i] = (bin << 16) | r;              // r < 16384 fits 16b
        }
    }
    __syncthreads();
    for (int b = threadIdx.x; b < B; b += PART_THREADS) {
        int c = lcnt[b];
        lbase[b] = (c > 0) ? atomicAdd(&gCnt[b], c) : 0;  // native int atomic
    }
    __syncthreads();
#pragma unroll
    for (int i = 0; i < PART_EPT; ++i) {
        if (binrank[i] >= 0) {
            int bin = binrank[i] >> 16;
            int r = binrank[i] & 0xFFFF;
            long long pos = (long long)lbase[bin] + r;
            if (pos < cap)
                slots[(size_t)bin * cap + pos] = pay[i];
        }
    }
}

// 4-wide slot fetch with sentinel-0 fill (w=0 -> no-op adds). Cached loads.
__device__ __forceinline__ void load4(const u64* __restrict__ sp, int j, int c,
                                      u64& v0, u64& v1, u64& v2, u64& v3) {
    v0 = v1 = v2 = v3 = 0;
    if (j + 3 < c) {
        ll2 q0 = *((const ll2*)(sp + j));
        ll2 q1 = *((const ll2*)(sp + j) + 1);
        v0 = (u64)q0.x; v1 = (u64)q0.y; v2 = (u64)q1.x; v3 = (u64)q1.y;
    } else if (j < c) {
        v0 = sp[j];
        if (j + 1 < c) v1 = sp[j + 1];
        if (j + 2 < c) v2 = sp[j + 2];
    }
}

// Per-bin: deg[n] = 1 + sum w; dinv = rsqrt(deg); y[n] = fp16(x[n]*dinv).
// Fixed-point int accumulation (native ds_add_u32).
__global__ __launch_bounds__(AGG_THREADS, 4)
void k_deg_dinv(const u64* __restrict__ slots, const int* __restrict__ gCnt,
                const float4* __restrict__ x, float* __restrict__ dinv,
                h4* __restrict__ y, int N, int cap) {
    __shared__ int degLds[NPB];
    const int b = blockIdx.x;
    for (int t = threadIdx.x; t < NPB; t += AGG_THREADS) degLds[t] = 0;
    __syncthreads();
    const int c = min(gCnt[b], cap);
    const u64* sp = slots + (size_t)b * cap;
    const int CH = AGG_THREADS * 4;
    for (int base = 0; base < c; base += CH) {
        int j = base + (threadIdx.x << 2);
        u64 v0, v1, v2, v3;
        load4(sp, j, c, v0, v1, v2, v3);
        atomicAdd(&degLds[((unsigned)v0) >> 23],
                  __float2int_rn(__uint_as_float((unsigned)(v0 >> 32)) * DEG_SCALE));
        atomicAdd(&degLds[((unsigned)v1) >> 23],
                  __float2int_rn(__uint_as_float((unsigned)(v1 >> 32)) * DEG_SCALE));
        atomicAdd(&degLds[((unsigned)v2) >> 23],
                  __float2int_rn(__uint_as_float((unsigned)(v2 >> 32)) * DEG_SCALE));
        atomicAdd(&degLds[((unsigned)v3) >> 23],
                  __float2int_rn(__uint_as_float((unsigned)(v3 >> 32)) * DEG_SCALE));
    }
    __syncthreads();
    for (int t = threadIdx.x; t < NPB; t += AGG_THREADS) {
        int n = (b << NPB_SHIFT) + t;
        if (n < N) {
            float deg = 1.0f + (float)degLds[t] * DEG_INV;
            float di = rsqrtf(deg);
            dinv[n] = di;
            float4 xv = x[n];
            h4 hv;
            hv.a = __floats2half2_rn(xv.x * di, xv.y * di);
            hv.b = __floats2half2_rn(xv.z * di, xv.w * di);
            y[n] = hv;
        }
    }
}

// Per-bin layer1 aggregation + fused MLP: z[n] = dinv[n]*MLP(di*(y[n]+sum w*y[s]))
__global__ __launch_bounds__(AGG_THREADS, 4)
void k_layer1(const u64* __restrict__ slots, const int* __restrict__ gCnt,
              const float* __restrict__ dinv, const h4* __restrict__ yh,
              const float* __restrict__ W1, const float* __restrict__ b1,
              const float* __restrict__ W2, float* __restrict__ z,
              int N, int cap) {
    __shared__ int acc[NPB][5];   // stride 5 -> 32-bank spread; int fixed-point
    __shared__ float dLds[NPB];
    __shared__ float sW1[64], sb1[16], sW2[16];
    if (threadIdx.x < 64) sW1[threadIdx.x] = W1[threadIdx.x];
    if (threadIdx.x < 16) {
        sb1[threadIdx.x] = b1[threadIdx.x];
        sW2[threadIdx.x] = W2[threadIdx.x];
    }
    const int b = blockIdx.x;
    for (int t = threadIdx.x; t < NPB; t += AGG_THREADS) {
        acc[t][0] = acc[t][1] = acc[t][2] = acc[t][3] = 0;
        int n = (b << NPB_SHIFT) + t;
        dLds[t] = (n < N) ? dinv[n] : 0.0f;
    }
    __syncthreads();
    const int c = min(gCnt[b], cap);
    const u64* sp = slots + (size_t)b * cap;
    const int CH = AGG_THREADS * 4;
    for (int base = 0; base < c; base += CH) {
        int j = base + (threadIdx.x << 2);
        u64 v0, v1, v2, v3;
        load4(sp, j, c, v0, v1, v2, v3);
        unsigned pk0 = (unsigned)v0, pk1 = (unsigned)v1,
                 pk2 = (unsigned)v2, pk3 = (unsigned)v3;
        float w0 = __uint_as_float((unsigned)(v0 >> 32));
        float w1 = __uint_as_float((unsigned)(v1 >> 32));
        float w2 = __uint_as_float((unsigned)(v2 >> 32));
        float w3 = __uint_as_float((unsigned)(v3 >> 32));
        // 4 independent gathers in flight
        h4 g0 = yh[pk0 & 0x7FFFFF];
        h4 g1 = yh[pk1 & 0x7FFFFF];
        h4 g2 = yh[pk2 & 0x7FFFFF];
        h4 g3 = yh[pk3 & 0x7FFFFF];
        float4 f0 = h4_to_f4(g0), f1 = h4_to_f4(g1),
               f2 = h4_to_f4(g2), f3 = h4_to_f4(g3);
        int d0 = pk0 >> 23, d1 = pk1 >> 23, d2 = pk2 >> 23, d3 = pk3 >> 23;
        atomicAdd(&acc[d0][0], __float2int_rn(w0 * f0.x * A1_SCALE));
        atomicAdd(&acc[d0][1], __float2int_rn(w0 * f0.y * A1_SCALE));
        atomicAdd(&acc[d0][2], __float2int_rn(w0 * f0.z * A1_SCALE));
        atomicAdd(&acc[d0][3], __float2int_rn(w0 * f0.w * A1_SCALE));
        atomicAdd(&acc[d1][0], __float2int_rn(w1 * f1.x * A1_SCALE));
        atomicAdd(&acc[d1][1], __float2int_rn(w1 * f1.y * A1_SCALE));
        atomicAdd(&acc[d1][2], __float2int_rn(w1 * f1.z * A1_SCALE));
        atomicAdd(&acc[d1][3], __float2int_rn(w1 * f1.w * A1_SCALE));
        atomicAdd(&acc[d2][0], __float2int_rn(w2 * f2.x * A1_SCALE));
        atomicAdd(&acc[d2][1], __float2int_rn(w2 * f2.y * A1_SCALE));
        atomicAdd(&acc[d2][2], __float2int_rn(w2 * f2.z * A1_SCALE));
        atomicAdd(&acc[d2][3], __float2int_rn(w2 * f2.w * A1_SCALE));
        atomicAdd(&acc[d3][0], __float2int_rn(w3 * f3.x * A1_SCALE));
        atomicAdd(&acc[d3][1], __float2int_rn(w3 * f3.y * A1_SCALE));
        atomicAdd(&acc[d3][2], __float2int_rn(w3 * f3.z * A1_SCALE));
        atomicAdd(&acc[d3][3], __float2int_rn(w3 * f3.w * A1_SCALE));
    }
    __syncthreads();
    for (int t = threadIdx.x; t < NPB; t += AGG_THREADS) {
        int n = (b << NPB_SHIFT) + t;
        if (n >= N) continue;
        float di = dLds[t];
        float4 yv = h4_to_f4(yh[n]);
        float ax = di * (yv.x + (float)acc[t][0] * A1_INV);
        float ay = di * (yv.y + (float)acc[t][1] * A1_INV);
        float az = di * (yv.z + (float)acc[t][2] * A1_INV);
        float aw = di * (yv.w + (float)acc[t][3] * A1_INV);
        float sacc = 0.0f;
#pragma unroll
        for (int k = 0; k < 16; ++k) {
            float h = ax * sW1[k] + ay * sW1[16 + k] + az * sW1[32 + k]
                    + aw * sW1[48 + k] + sb1[k];
            sacc += fmaxf(h, 0.0f) * sW2[k];
        }
        z[n] = sacc * di;
    }
}

// Per-bin layer2: out[n] = di*(z[n] + sum w*z[s]) + b2
__global__ __launch_bounds__(AGG_THREADS, 4)
void k_layer2(const u64* __restrict__ slots, const int* __restrict__ gCnt,
              const float* __restrict__ dinv, const float* __restrict__ z,
              const float* __restrict__ b2, float* __restrict__ out,
              int N, int cap) {
    __shared__ int accs[NPB];
    __shared__ float dLds[NPB];
    const int b = blockIdx.x;
    for (int t = threadIdx.x; t < NPB; t += AGG_THREADS) {
        accs[t] = 0;
        int n = (b << NPB_SHIFT) + t;
        dLds[t] = (n < N) ? dinv[n] : 0.0f;
    }
    __syncthreads();
    const int c = min(gCnt[b], cap);
    const u64* sp = slots + (size_t)b * cap;
    const int CH = AGG_THREADS * 4;
    for (int base = 0; base < c; base += CH) {
        int j = base + (threadIdx.x << 2);
        u64 v0, v1, v2, v3;
        load4(sp, j, c, v0, v1, v2, v3);
        unsigned pk0 = (unsigned)v0, pk1 = (unsigned)v1,
                 pk2 = (unsigned)v2, pk3 = (unsigned)v3;
        float z0 = z[pk0 & 0x7FFFFF];
        float z1 = z[pk1 & 0x7FFFFF];
        float z2 = z[pk2 & 0x7FFFFF];
        float z3 = z[pk3 & 0x7FFFFF];
        atomicAdd(&accs[pk0 >> 23],
                  __float2int_rn(__uint_as_float((unsigned)(v0 >> 32)) * z0 * A2_SCALE));
        atomicAdd(&accs[pk1 >> 23],
                  __float2int_rn(__uint_as_float((unsigned)(v1 >> 32)) * z1 * A2_SCALE));
        atomicAdd(&accs[pk2 >> 23],
                  __float2int_rn(__uint_as_float((unsigned)(v2 >> 32)) * z2 * A2_SCALE));
        atomicAdd(&accs[pk3 >> 23],
                  __float2int_rn(__uint_as_float((unsigned)(v3 >> 32)) * z3 * A2_SCALE));
    }
    __syncthreads();
    const float bb2 = b2[0];
    for (int t = threadIdx.x; t < NPB; t += AGG_THREADS) {
        int n = (b << NPB_SHIFT) + t;
        if (n < N) out[n] = dLds[t] * (z[n] + (float)accs[t] * A2_INV) + bb2;
    }
}

// ------------------------- fallback (round-1) path -------------------------
__global__ __launch_bounds__(256)
void k_init(float* __restrict__ deg, int N) {
    int i = blockIdx.x * blockDim.x + threadIdx.x;
    if (i < N) deg[i] = 1.0f;
}

__global__ __launch_bounds__(256)
void k_deg(const void* __restrict__ idx, const float* __restrict__ ew,
           float* __restrict__ deg, int E, const int* __restrict__ flag) {
    const bool is64 = (*flag != 0);
    const int stride = gridDim.x * blockDim.x;
    for (int e = blockIdx.x * blockDim.x + threadIdx.x; e < E; e += stride) {
        int d = is64 ? (int)((const long long*)idx)[(long long)E + e]
                     : ((const int*)idx)[E + e];
        atomicAdd(deg + d, ew[e]);
    }
}

__global__ __launch_bounds__(256)
void k_dinv_accx(float* __restrict__ deg_dinv, const float4* __restrict__ x,
                 float4* __restrict__ accx, int N) {
    int n = blockIdx.x * blockDim.x + threadIdx.x;
    if (n >= N) return;
    float dg = deg_dinv[n];
    float di = (dg > 0.0f) ? rsqrtf(dg) : 0.0f;
    deg_dinv[n] = di;
    float sn = di * di;
    float4 xv = x[n];
    accx[n] = make_float4(xv.x * sn, xv.y * sn, xv.z * sn, xv.w * sn);
}

__global__ __launch_bounds__(256)
void k_scatter1(const void* __restrict__ idx, const float* __restrict__ ew,
                const float* __restrict__ dinv, const float4* __restrict__ x,
                float* __restrict__ accx, int E, const int* __restrict__ flag) {
    const bool is64 = (*flag != 0);
    const int stride = gridDim.x * blockDim.x;
    for (int e = blockIdx.x * blockDim.x + threadIdx.x; e < E; e += stride) {
        int s, d;
        if (is64) {
            const long long* p = (const long long*)idx;
            s = (int)p[e]; d = (int)p[(long long)E + e];
        } else {
            const int* p = (const int*)idx;
            s = p[e]; d = p[E + e];
        }
        float nm = dinv[s] * ew[e] * dinv[d];
        float4 xv = x[s];
        float* dp = accx + (size_t)d * 4;
        atomicAdd(dp + 0, nm * xv.x);
        atomicAdd(dp + 1, nm * xv.y);
        atomicAdd(dp + 2, nm * xv.z);
        atomicAdd(dp + 3, nm * xv.w);
    }
}

__global__ __launch_bounds__(256)
void k_node2(const float4* __restrict__ accx, const float* __restrict__ dinv,
             const float* __restrict__ W1, const float* __restrict__ b1,
             const float* __restrict__ W2, const float* __restrict__ b2,
             float* __restrict__ s2, float* __restrict__ out, int N) {
    __shared__ float sW1[64], sb1[16], sW2[16];
    if (threadIdx.x < 64) sW1[threadIdx.x] = W1[threadIdx.x];
    if (threadIdx.x < 16) {
        sb1[threadIdx.x] = b1[threadIdx.x];
        sW2[threadIdx.x] = W2[threadIdx.x];
    }
    __syncthreads();
    int n = blockIdx.x * blockDim.x + threadIdx.x;
    if (n >= N) return;
    float bb2 = b2[0];
    float4 a = accx[n];
    float acc = 0.0f;
#pragma unroll
    for (int k = 0; k < 16; ++k) {
        float h = a.x * sW1[k] + a.y * sW1[16 + k] + a.z * sW1[32 + k]
                + a.w * sW1[48 + k] + sb1[k];
        acc += fmaxf(h, 0.0f) * sW2[k];
    }
    s2[n] = acc;
    float di = dinv[n];
    out[n] = acc * di * di + bb2;
}

__global__ __launch_bounds__(256)
void k_scatter2(const void* __restrict__ idx, const float* __restrict__ ew,
                const float* __restrict__ dinv, const float* __restrict__ s2,
                float* __restrict__ out, int E, const int* __restrict__ flag) {
    const bool is64 = (*flag != 0);
    const int stride = gridDim.x * blockDim.x;
    for (int e = blockIdx.x * blockDim.x + threadIdx.x; e < E; e += stride) {
        int s, d;
        if (is64) {
            const long long* p = (const long long*)idx;
            s = (int)p[e]; d = (int)p[(long long)E + e];
        } else {
            const int* p = (const int*)idx;
            s = p[e]; d = p[E + e];
        }
        float nm = dinv[s] * ew[e] * dinv[d];
        atomicAdd(out + d, nm * s2[s]);
    }
}

// ---------------------------------------------------------------------------
extern "C" void kernel_launch(void* const* d_in, const int* in_sizes, int n_in,
                              void* d_out, int out_size, void* d_ws, size_t ws_size,
                              hipStream_t stream) {
    const float* x   = (const float*)d_in[0];
    const void*  eix = d_in[1];
    const float* ew  = (const float*)d_in[2];
    const float* W1  = (const float*)d_in[3];
    const float* b1  = (const float*)d_in[4];
    const float* W2  = (const float*)d_in[5];
    const float* b2  = (const float*)d_in[6];
    float* out = (float*)d_out;

    const int N = in_sizes[0] / 4;   // x is [N,4]
    const int E = in_sizes[2];       // edge_weight is [E]

    const int B = (N + NPB - 1) >> NPB_SHIFT;
    int cap = (E / B + 2048 + 3) & ~3;   // mean + ~23 sigma, multiple of 4
    const int nCheck = (E < 65536) ? E : 65536;

    // ws: y [N h4=8B] | slots [B*cap u64] | gCnt [B] | dinv [N] | z [N] | flag
    size_t need = (size_t)N * 8 + (size_t)B * cap * 8
                + (size_t)B * 4 + (size_t)N * 8 + 256;

    if (B <= MAX_BINS && N < (1 << 23) && ws_size >= need) {
        h4* y = (h4*)d_ws;
        u64* slots = (u64*)(y + N);
        int*   gCnt = (int*)(slots + (size_t)B * cap);
        float* dinv = (float*)(gCnt + B);
        float* z    = dinv + N;
        int*   flag = (int*)(z + N);

        const int part_blocks = (E + PART_EPT * PART_THREADS - 1) / (PART_EPT * PART_THREADS);

        k_zero<<<(B + 255) / 256, 256, 0, stream>>>(gCnt, B);
        k_detect<<<1, 1024, 0, stream>>>((const unsigned int*)eix, nCheck, flag);
        k_partition<<<part_blocks, PART_THREADS, 0, stream>>>(eix, ew, gCnt, slots,
                                                              E, B, cap, flag);
        k_deg_dinv<<<B, AGG_THREADS, 0, stream>>>(slots, gCnt, (const float4*)x,
                                                  dinv, y, N, cap);
        k_layer1<<<B, AGG_THREADS, 0, stream>>>(slots, gCnt, dinv, y, W1, b1, W2,
                                                z, N, cap);
        k_layer2<<<B, AGG_THREADS, 0, stream>>>(slots, gCnt, dinv, z, b2, out, N, cap);
    } else {
        // fallback: direct atomic scatter (round-1)
        const int nb_n = (N + 255) / 256;
        const int nb_e = min((E + 255) / 256, 16384);
        float* deg  = (float*)d_ws;
        float* accx = deg + N;
        float* s2   = accx + (size_t)4 * N;
        int*   flag = (int*)(s2 + N);

        k_init<<<nb_n, 256, 0, stream>>>(deg, N);
        k_detect<<<1, 1024, 0, stream>>>((const unsigned int*)eix, nCheck, flag);
        k_deg<<<nb_e, 256, 0, stream>>>(eix, ew, deg, E, flag);
        k_dinv_accx<<<nb_n, 256, 0, stream>>>(deg, (const float4*)x, (float4*)accx, N);
        k_scatter1<<<nb_e, 256, 0, stream>>>(eix, ew, deg, (const float4*)x, accx, E, flag);
        k_node2<<<nb_n, 256, 0, stream>>>((const float4*)accx, deg, W1, b1, W2, b2, s2, out, N);
        k_scatter2<<<nb_e, 256, 0, stream>>>(eix, ew, deg, s2, out, E, flag);
    }
}

// Round 8
// 242.500 us; speedup vs baseline: 2.0273x; 1.0571x over previous
//
#include <hip/hip_runtime.h>
#include <hip/hip_fp16.h>

// ---------------------------------------------------------------------------
// CrowdGNN: 2-layer GCN, N=500k nodes, E=8M edges (+ implicit self loops).
// Round-8: partition was write-scatter bound (234MB HBM writes for 64MB of
// payload: 64 lanes -> 64 random 32B sectors per store). Fix: bin-sorted
// staging via LDS. Per 4096-edge block:
//   1) LDS-rank per bin (native int atomics)
//   2) exclusive scan of bin counts (wave shfl scan) + 1 global atomic per
//      non-empty (block,bin) for the slot base
//   3) stage (pay, globalAddr) into LDS in bin order
//   4) store staged order -> consecutive lanes hit consecutive addresses
// Agg kernels unchanged from round 7 (fixed-point int LDS atomics: native
// ds_add_u32; fp16 y table L2-resident; 4-wide unrolled slot loop).
// ---------------------------------------------------------------------------

typedef unsigned long long u64;
typedef long long ll2 __attribute__((ext_vector_type(2)));

#define NPB_SHIFT 9
#define NPB 512
#define MAX_BINS 1024
#define PART_THREADS 1024
#define PART_EPT 4
#define PART_CHUNK (PART_THREADS * PART_EPT)   // 4096 edges per block
#define AGG_THREADS 512

#define DEG_SCALE  16777216.0f   // 2^24
#define DEG_INV    (1.0f / 16777216.0f)
#define A1_SCALE   4194304.0f    // 2^22
#define A1_INV     (1.0f / 4194304.0f)
#define A2_SCALE   1048576.0f    // 2^20
#define A2_INV     (1.0f / 1048576.0f)

struct h4 { __half2 a, b; };

__device__ __forceinline__ float4 h4_to_f4(h4 v) {
    float2 lo = __half22float2(v.a);
    float2 hi = __half22float2(v.b);
    return make_float4(lo.x, lo.y, hi.x, hi.y);
}

// Detect int64 vs int32 edge_index: int64 values < 2^31 => odd words all zero.
__global__ __launch_bounds__(1024)
void k_detect(const unsigned int* __restrict__ idx_words, int nCheck, int* flag) {
    __shared__ int cnt;
    if (threadIdx.x == 0) cnt = 0;
    __syncthreads();
    int local = 0;
    for (int i = threadIdx.x; i < nCheck; i += blockDim.x)
        local += (idx_words[2 * i + 1] != 0u) ? 1 : 0;
    if (local) atomicAdd(&cnt, local);
    __syncthreads();
    if (threadIdx.x == 0) *flag = (cnt < 8) ? 1 : 0;
}

__global__ __launch_bounds__(256)
void k_zero(int* __restrict__ p, int n) {
    int i = blockIdx.x * blockDim.x + threadIdx.x;
    if (i < n) p[i] = 0;
}

// Bin-sorted-staging partition. Block = 1024 thr x 4 edges = 4096 edges.
__global__ __launch_bounds__(PART_THREADS)
void k_partition(const void* __restrict__ idx, const float* __restrict__ ew,
                 int* __restrict__ gCnt, u64* __restrict__ slots,
                 int E, int B, int cap, const int* __restrict__ flag) {
    __shared__ int lcnt[MAX_BINS];
    __shared__ int lbase[MAX_BINS];
    __shared__ int lstart[MAX_BINS];
    __shared__ u64 sPay[PART_CHUNK];
    __shared__ unsigned sAddr[PART_CHUNK];
    __shared__ int waveSum[PART_THREADS / 64];

    const bool is64 = (*flag != 0);
    const int tid = threadIdx.x;
    for (int i = tid; i < MAX_BINS; i += PART_THREADS) lcnt[i] = 0;
    __syncthreads();

    const int base_e = blockIdx.x * PART_CHUNK;
    const int nValid = min(PART_CHUNK, E - base_e);

    u64 pay[PART_EPT];
    int bin_[PART_EPT], r_[PART_EPT];
#pragma unroll
    for (int i = 0; i < PART_EPT; ++i) {
        int e = base_e + i * PART_THREADS + tid;
        bin_[i] = -1;
        if (e < E) {
            int s, d;
            if (is64) {
                const long long* p = (const long long*)idx;
                s = (int)__builtin_nontemporal_load(p + e);
                d = (int)__builtin_nontemporal_load(p + (long long)E + e);
            } else {
                const int* p = (const int*)idx;
                s = __builtin_nontemporal_load(p + e);
                d = __builtin_nontemporal_load(p + E + e);
            }
            float w = __builtin_nontemporal_load(ew + e);
            int bin = d >> NPB_SHIFT;
            unsigned pk = ((unsigned)(d & (NPB - 1)) << 23) | (unsigned)s;
            pay[i] = ((u64)__float_as_uint(w) << 32) | pk;
            bin_[i] = bin;
            r_[i] = atomicAdd(&lcnt[bin], 1);   // native ds_add, block-local rank
        }
    }
    __syncthreads();

    // Exclusive prefix scan of lcnt[0..1023] -> lstart; global base -> lbase.
    {
        const int lane = tid & 63, wid = tid >> 6;
        const int v = lcnt[tid];
        int inc = v;
#pragma unroll
        for (int off = 1; off < 64; off <<= 1) {
            int t = __shfl_up(inc, off, 64);
            if (lane >= off) inc += t;
        }
        if (lane == 63) waveSum[wid] = inc;
        __syncthreads();
        if (wid == 0) {
            const int NW = PART_THREADS / 64;
            int wv = (lane < NW) ? waveSum[lane] : 0;
            int winc = wv;
#pragma unroll
            for (int off = 1; off < NW; off <<= 1) {
                int t = __shfl_up(winc, off, 64);
                if (lane >= off) winc += t;
            }
            if (lane < NW) waveSum[lane] = winc - wv;  // exclusive wave offsets
        }
        __syncthreads();
        lstart[tid] = inc - v + waveSum[wid];
        lbase[tid] = (v > 0 && tid < B) ? atomicAdd(&gCnt[tid], v) : 0;
    }
    __syncthreads();

    // Stage in bin-sorted order.
#pragma unroll
    for (int i = 0; i < PART_EPT; ++i) {
        if (bin_[i] >= 0) {
            int si = lstart[bin_[i]] + r_[i];
            long long pos = (long long)lbase[bin_[i]] + r_[i];
            sPay[si] = pay[i];
            sAddr[si] = (pos < cap)
                      ? (unsigned)((long long)bin_[i] * cap + pos)
                      : 0xFFFFFFFFu;   // overflow guard (never expected)
        }
    }
    __syncthreads();

    // Coalesced store: consecutive k -> consecutive addresses within bin runs.
    for (int k = tid; k < nValid; k += PART_THREADS) {
        unsigned a = sAddr[k];
        if (a != 0xFFFFFFFFu) slots[a] = sPay[k];
    }
}

// 4-wide slot fetch with sentinel-0 fill (w=0 -> no-op adds). Cached loads.
__device__ __forceinline__ void load4(const u64* __restrict__ sp, int j, int c,
                                      u64& v0, u64& v1, u64& v2, u64& v3) {
    v0 = v1 = v2 = v3 = 0;
    if (j + 3 < c) {
        ll2 q0 = *((const ll2*)(sp + j));
        ll2 q1 = *((const ll2*)(sp + j) + 1);
        v0 = (u64)q0.x; v1 = (u64)q0.y; v2 = (u64)q1.x; v3 = (u64)q1.y;
    } else if (j < c) {
        v0 = sp[j];
        if (j + 1 < c) v1 = sp[j + 1];
        if (j + 2 < c) v2 = sp[j + 2];
    }
}

// Per-bin: deg[n] = 1 + sum w; dinv = rsqrt(deg); y[n] = fp16(x[n]*dinv).
__global__ __launch_bounds__(AGG_THREADS, 4)
void k_deg_dinv(const u64* __restrict__ slots, const int* __restrict__ gCnt,
                const float4* __restrict__ x, float* __restrict__ dinv,
                h4* __restrict__ y, int N, int cap) {
    __shared__ int degLds[NPB];
    const int b = blockIdx.x;
    for (int t = threadIdx.x; t < NPB; t += AGG_THREADS) degLds[t] = 0;
    __syncthreads();
    const int c = min(gCnt[b], cap);
    const u64* sp = slots + (size_t)b * cap;
    const int CH = AGG_THREADS * 4;
    for (int base = 0; base < c; base += CH) {
        int j = base + (threadIdx.x << 2);
        u64 v0, v1, v2, v3;
        load4(sp, j, c, v0, v1, v2, v3);
        atomicAdd(&degLds[((unsigned)v0) >> 23],
                  __float2int_rn(__uint_as_float((unsigned)(v0 >> 32)) * DEG_SCALE));
        atomicAdd(&degLds[((unsigned)v1) >> 23],
                  __float2int_rn(__uint_as_float((unsigned)(v1 >> 32)) * DEG_SCALE));
        atomicAdd(&degLds[((unsigned)v2) >> 23],
                  __float2int_rn(__uint_as_float((unsigned)(v2 >> 32)) * DEG_SCALE));
        atomicAdd(&degLds[((unsigned)v3) >> 23],
                  __float2int_rn(__uint_as_float((unsigned)(v3 >> 32)) * DEG_SCALE));
    }
    __syncthreads();
    for (int t = threadIdx.x; t < NPB; t += AGG_THREADS) {
        int n = (b << NPB_SHIFT) + t;
        if (n < N) {
            float deg = 1.0f + (float)degLds[t] * DEG_INV;
            float di = rsqrtf(deg);
            dinv[n] = di;
            float4 xv = x[n];
            h4 hv;
            hv.a = __floats2half2_rn(xv.x * di, xv.y * di);
            hv.b = __floats2half2_rn(xv.z * di, xv.w * di);
            y[n] = hv;
        }
    }
}

// Per-bin layer1 aggregation + fused MLP: z[n] = dinv[n]*MLP(di*(y[n]+sum w*y[s]))
__global__ __launch_bounds__(AGG_THREADS, 4)
void k_layer1(const u64* __restrict__ slots, const int* __restrict__ gCnt,
              const float* __restrict__ dinv, const h4* __restrict__ yh,
              const float* __restrict__ W1, const float* __restrict__ b1,
              const float* __restrict__ W2, float* __restrict__ z,
              int N, int cap) {
    __shared__ int acc[NPB][5];   // stride 5 -> 32-bank spread; int fixed-point
    __shared__ float dLds[NPB];
    __shared__ float sW1[64], sb1[16], sW2[16];
    if (threadIdx.x < 64) sW1[threadIdx.x] = W1[threadIdx.x];
    if (threadIdx.x < 16) {
        sb1[threadIdx.x] = b1[threadIdx.x];
        sW2[threadIdx.x] = W2[threadIdx.x];
    }
    const int b = blockIdx.x;
    for (int t = threadIdx.x; t < NPB; t += AGG_THREADS) {
        acc[t][0] = acc[t][1] = acc[t][2] = acc[t][3] = 0;
        int n = (b << NPB_SHIFT) + t;
        dLds[t] = (n < N) ? dinv[n] : 0.0f;
    }
    __syncthreads();
    const int c = min(gCnt[b], cap);
    const u64* sp = slots + (size_t)b * cap;
    const int CH = AGG_THREADS * 4;
    for (int base = 0; base < c; base += CH) {
        int j = base + (threadIdx.x << 2);
        u64 v0, v1, v2, v3;
        load4(sp, j, c, v0, v1, v2, v3);
        unsigned pk0 = (unsigned)v0, pk1 = (unsigned)v1,
                 pk2 = (unsigned)v2, pk3 = (unsigned)v3;
        float w0 = __uint_as_float((unsigned)(v0 >> 32));
        float w1 = __uint_as_float((unsigned)(v1 >> 32));
        float w2 = __uint_as_float((unsigned)(v2 >> 32));
        float w3 = __uint_as_float((unsigned)(v3 >> 32));
        // 4 independent gathers in flight
        h4 g0 = yh[pk0 & 0x7FFFFF];
        h4 g1 = yh[pk1 & 0x7FFFFF];
        h4 g2 = yh[pk2 & 0x7FFFFF];
        h4 g3 = yh[pk3 & 0x7FFFFF];
        float4 f0 = h4_to_f4(g0), f1 = h4_to_f4(g1),
               f2 = h4_to_f4(g2), f3 = h4_to_f4(g3);
        int d0 = pk0 >> 23, d1 = pk1 >> 23, d2 = pk2 >> 23, d3 = pk3 >> 23;
        atomicAdd(&acc[d0][0], __float2int_rn(w0 * f0.x * A1_SCALE));
        atomicAdd(&acc[d0][1], __float2int_rn(w0 * f0.y * A1_SCALE));
        atomicAdd(&acc[d0][2], __float2int_rn(w0 * f0.z * A1_SCALE));
        atomicAdd(&acc[d0][3], __float2int_rn(w0 * f0.w * A1_SCALE));
        atomicAdd(&acc[d1][0], __float2int_rn(w1 * f1.x * A1_SCALE));
        atomicAdd(&acc[d1][1], __float2int_rn(w1 * f1.y * A1_SCALE));
        atomicAdd(&acc[d1][2], __float2int_rn(w1 * f1.z * A1_SCALE));
        atomicAdd(&acc[d1][3], __float2int_rn(w1 * f1.w * A1_SCALE));
        atomicAdd(&acc[d2][0], __float2int_rn(w2 * f2.x * A1_SCALE));
        atomicAdd(&acc[d2][1], __float2int_rn(w2 * f2.y * A1_SCALE));
        atomicAdd(&acc[d2][2], __float2int_rn(w2 * f2.z * A1_SCALE));
        atomicAdd(&acc[d2][3], __float2int_rn(w2 * f2.w * A1_SCALE));
        atomicAdd(&acc[d3][0], __float2int_rn(w3 * f3.x * A1_SCALE));
        atomicAdd(&acc[d3][1], __float2int_rn(w3 * f3.y * A1_SCALE));
        atomicAdd(&acc[d3][2], __float2int_rn(w3 * f3.z * A1_SCALE));
        atomicAdd(&acc[d3][3], __float2int_rn(w3 * f3.w * A1_SCALE));
    }
    __syncthreads();
    for (int t = threadIdx.x; t < NPB; t += AGG_THREADS) {
        int n = (b << NPB_SHIFT) + t;
        if (n >= N) continue;
        float di = dLds[t];
        float4 yv = h4_to_f4(yh[n]);
        float ax = di * (yv.x + (float)acc[t][0] * A1_INV);
        float ay = di * (yv.y + (float)acc[t][1] * A1_INV);
        float az = di * (yv.z + (float)acc[t][2] * A1_INV);
        float aw = di * (yv.w + (float)acc[t][3] * A1_INV);
        float sacc = 0.0f;
#pragma unroll
        for (int k = 0; k < 16; ++k) {
            float h = ax * sW1[k] + ay * sW1[16 + k] + az * sW1[32 + k]
                    + aw * sW1[48 + k] + sb1[k];
            sacc += fmaxf(h, 0.0f) * sW2[k];
        }
        z[n] = sacc * di;
    }
}

// Per-bin layer2: out[n] = di*(z[n] + sum w*z[s]) + b2
__global__ __launch_bounds__(AGG_THREADS, 4)
void k_layer2(const u64* __restrict__ slots, const int* __restrict__ gCnt,
              const float* __restrict__ dinv, const float* __restrict__ z,
              const float* __restrict__ b2, float* __restrict__ out,
              int N, int cap) {
    __shared__ int accs[NPB];
    __shared__ float dLds[NPB];
    const int b = blockIdx.x;
    for (int t = threadIdx.x; t < NPB; t += AGG_THREADS) {
        accs[t] = 0;
        int n = (b << NPB_SHIFT) + t;
        dLds[t] = (n < N) ? dinv[n] : 0.0f;
    }
    __syncthreads();
    const int c = min(gCnt[b], cap);
    const u64* sp = slots + (size_t)b * cap;
    const int CH = AGG_THREADS * 4;
    for (int base = 0; base < c; base += CH) {
        int j = base + (threadIdx.x << 2);
        u64 v0, v1, v2, v3;
        load4(sp, j, c, v0, v1, v2, v3);
        unsigned pk0 = (unsigned)v0, pk1 = (unsigned)v1,
                 pk2 = (unsigned)v2, pk3 = (unsigned)v3;
        float z0 = z[pk0 & 0x7FFFFF];
        float z1 = z[pk1 & 0x7FFFFF];
        float z2 = z[pk2 & 0x7FFFFF];
        float z3 = z[pk3 & 0x7FFFFF];
        atomicAdd(&accs[pk0 >> 23],
                  __float2int_rn(__uint_as_float((unsigned)(v0 >> 32)) * z0 * A2_SCALE));
        atomicAdd(&accs[pk1 >> 23],
                  __float2int_rn(__uint_as_float((unsigned)(v1 >> 32)) * z1 * A2_SCALE));
        atomicAdd(&accs[pk2 >> 23],
                  __float2int_rn(__uint_as_float((unsigned)(v2 >> 32)) * z2 * A2_SCALE));
        atomicAdd(&accs[pk3 >> 23],
                  __float2int_rn(__uint_as_float((unsigned)(v3 >> 32)) * z3 * A2_SCALE));
    }
    __syncthreads();
    const float bb2 = b2[0];
    for (int t = threadIdx.x; t < NPB; t += AGG_THREADS) {
        int n = (b << NPB_SHIFT) + t;
        if (n < N) out[n] = dLds[t] * (z[n] + (float)accs[t] * A2_INV) + bb2;
    }
}

// ------------------------- fallback (round-1) path -------------------------
__global__ __launch_bounds__(256)
void k_init(float* __restrict__ deg, int N) {
    int i = blockIdx.x * blockDim.x + threadIdx.x;
    if (i < N) deg[i] = 1.0f;
}

__global__ __launch_bounds__(256)
void k_deg(const void* __restrict__ idx, const float* __restrict__ ew,
           float* __restrict__ deg, int E, const int* __restrict__ flag) {
    const bool is64 = (*flag != 0);
    const int stride = gridDim.x * blockDim.x;
    for (int e = blockIdx.x * blockDim.x + threadIdx.x; e < E; e += stride) {
        int d = is64 ? (int)((const long long*)idx)[(long long)E + e]
                     : ((const int*)idx)[E + e];
        atomicAdd(deg + d, ew[e]);
    }
}

__global__ __launch_bounds__(256)
void k_dinv_accx(float* __restrict__ deg_dinv, const float4* __restrict__ x,
                 float4* __restrict__ accx, int N) {
    int n = blockIdx.x * blockDim.x + threadIdx.x;
    if (n >= N) return;
    float dg = deg_dinv[n];
    float di = (dg > 0.0f) ? rsqrtf(dg) : 0.0f;
    deg_dinv[n] = di;
    float sn = di * di;
    float4 xv = x[n];
    accx[n] = make_float4(xv.x * sn, xv.y * sn, xv.z * sn, xv.w * sn);
}

__global__ __launch_bounds__(256)
void k_scatter1(const void* __restrict__ idx, const float* __restrict__ ew,
                const float* __restrict__ dinv, const float4* __restrict__ x,
                float* __restrict__ accx, int E, const int* __restrict__ flag) {
    const bool is64 = (*flag != 0);
    const int stride = gridDim.x * blockDim.x;
    for (int e = blockIdx.x * blockDim.x + threadIdx.x; e < E; e += stride) {
        int s, d;
        if (is64) {
            const long long* p = (const long long*)idx;
            s = (int)p[e]; d = (int)p[(long long)E + e];
        } else {
            const int* p = (const int*)idx;
            s = p[e]; d = p[E + e];
        }
        float nm = dinv[s] * ew[e] * dinv[d];
        float4 xv = x[s];
        float* dp = accx + (size_t)d * 4;
        atomicAdd(dp + 0, nm * xv.x);
        atomicAdd(dp + 1, nm * xv.y);
        atomicAdd(dp + 2, nm * xv.z);
        atomicAdd(dp + 3, nm * xv.w);
    }
}

__global__ __launch_bounds__(256)
void k_node2(const float4* __restrict__ accx, const float* __restrict__ dinv,
             const float* __restrict__ W1, const float* __restrict__ b1,
             const float* __restrict__ W2, const float* __restrict__ b2,
             float* __restrict__ s2, float* __restrict__ out, int N) {
    __shared__ float sW1[64], sb1[16], sW2[16];
    if (threadIdx.x < 64) sW1[threadIdx.x] = W1[threadIdx.x];
    if (threadIdx.x < 16) {
        sb1[threadIdx.x] = b1[threadIdx.x];
        sW2[threadIdx.x] = W2[threadIdx.x];
    }
    __syncthreads();
    int n = blockIdx.x * blockDim.x + threadIdx.x;
    if (n >= N) return;
    float bb2 = b2[0];
    float4 a = accx[n];
    float acc = 0.0f;
#pragma unroll
    for (int k = 0; k < 16; ++k) {
        float h = a.x * sW1[k] + a.y * sW1[16 + k] + a.z * sW1[32 + k]
                + a.w * sW1[48 + k] + sb1[k];
        acc += fmaxf(h, 0.0f) * sW2[k];
    }
    s2[n] = acc;
    float di = dinv[n];
    out[n] = acc * di * di + bb2;
}

__global__ __launch_bounds__(256)
void k_scatter2(const void* __restrict__ idx, const float* __restrict__ ew,
                const float* __restrict__ dinv, const float* __restrict__ s2,
                float* __restrict__ out, int E, const int* __restrict__ flag) {
    const bool is64 = (*flag != 0);
    const int stride = gridDim.x * blockDim.x;
    for (int e = blockIdx.x * blockDim.x + threadIdx.x; e < E; e += stride) {
        int s, d;
        if (is64) {
            const long long* p = (const long long*)idx;
            s = (int)p[e]; d = (int)p[(long long)E + e];
        } else {
            const int* p = (const int*)idx;
            s = p[e]; d = p[E + e];
        }
        float nm = dinv[s] * ew[e] * dinv[d];
        atomicAdd(out + d, nm * s2[s]);
    }
}

// ---------------------------------------------------------------------------
extern "C" void kernel_launch(void* const* d_in, const int* in_sizes, int n_in,
                              void* d_out, int out_size, void* d_ws, size_t ws_size,
                              hipStream_t stream) {
    const float* x   = (const float*)d_in[0];
    const void*  eix = d_in[1];
    const float* ew  = (const float*)d_in[2];
    const float* W1  = (const float*)d_in[3];
    const float* b1  = (const float*)d_in[4];
    const float* W2  = (const float*)d_in[5];
    const float* b2  = (const float*)d_in[6];
    float* out = (float*)d_out;

    const int N = in_sizes[0] / 4;   // x is [N,4]
    const int E = in_sizes[2];       // edge_weight is [E]

    const int B = (N + NPB - 1) >> NPB_SHIFT;
    int cap = (E / B + 2048 + 3) & ~3;   // mean + ~23 sigma, multiple of 4
    const int nCheck = (E < 65536) ? E : 65536;

    // ws: y [N h4=8B] | slots [B*cap u64] | gCnt [B] | dinv [N] | z [N] | flag
    size_t need = (size_t)N * 8 + (size_t)B * cap * 8
                + (size_t)B * 4 + (size_t)N * 8 + 256;

    // u32 slot-address space check for the staged-store partition
    bool addr32ok = ((long long)B * cap) < 0xFFFFFFFFLL;

    if (B <= MAX_BINS && N < (1 << 23) && ws_size >= need && addr32ok) {
        h4* y = (h4*)d_ws;
        u64* slots = (u64*)(y + N);
        int*   gCnt = (int*)(slots + (size_t)B * cap);
        float* dinv = (float*)(gCnt + B);
        float* z    = dinv + N;
        int*   flag = (int*)(z + N);

        const int part_blocks = (E + PART_CHUNK - 1) / PART_CHUNK;

        k_zero<<<(B + 255) / 256, 256, 0, stream>>>(gCnt, B);
        k_detect<<<1, 1024, 0, stream>>>((const unsigned int*)eix, nCheck, flag);
        k_partition<<<part_blocks, PART_THREADS, 0, stream>>>(eix, ew, gCnt, slots,
                                                              E, B, cap, flag);
        k_deg_dinv<<<B, AGG_THREADS, 0, stream>>>(slots, gCnt, (const float4*)x,
                                                  dinv, y, N, cap);
        k_layer1<<<B, AGG_THREADS, 0, stream>>>(slots, gCnt, dinv, y, W1, b1, W2,
                                                z, N, cap);
        k_layer2<<<B, AGG_THREADS, 0, stream>>>(slots, gCnt, dinv, z, b2, out, N, cap);
    } else {
        // fallback: direct atomic scatter (round-1)
        const int nb_n = (N + 255) / 256;
        const int nb_e = min((E + 255) / 256, 16384);
        float* deg  = (float*)d_ws;
        float* accx = deg + N;
        float* s2   = accx + (size_t)4 * N;
        int*   flag = (int*)(s2 + N);

        k_init<<<nb_n, 256, 0, stream>>>(deg, N);
        k_detect<<<1, 1024, 0, stream>>>((const unsigned int*)eix, nCheck, flag);
        k_deg<<<nb_e, 256, 0, stream>>>(eix, ew, deg, E, flag);
        k_dinv_accx<<<nb_n, 256, 0, stream>>>(deg, (const float4*)x, (float4*)accx, N);
        k_scatter1<<<nb_e, 256, 0, stream>>>(eix, ew, deg, (const float4*)x, accx, E, flag);
        k_node2<<<nb_n, 256, 0, stream>>>((const float4*)accx, deg, W1, b1, W2, b2, s2, out, N);
        k_scatter2<<<nb_e, 256, 0, stream>>>(eix, ew, deg, s2, out, E, flag);
    }
}